// Round 1
// baseline (7750.887 us; speedup 1.0000x reference)
//
#include <hip/hip_runtime.h>
#include <hip/hip_bf16.h>
#include <math.h>

#define BDIM 256
#define L 64
#define D 38
#define H 2
#define HD 19
#define NL 6
#define KD 8
#define QKV (3*D)   // 114

__global__ __launch_bounds__(BDIM) void symptom_fused_kernel(
    const float* __restrict__ x_g,
    const float* __restrict__ in_proj_w,  // [NL][114][38]
    const float* __restrict__ in_proj_b,  // [NL][114]
    const float* __restrict__ out_w,      // [NL][38][38]
    const float* __restrict__ out_b,      // [NL][38]
    const float* __restrict__ lin1_w,     // [NL][38][38]
    const float* __restrict__ lin1_b,     // [NL][38]
    const float* __restrict__ lin2_w,     // [NL][38][38]
    const float* __restrict__ lin2_b,     // [NL][38]
    const float* __restrict__ ln1_w,      // [NL][38]
    const float* __restrict__ ln1_b,
    const float* __restrict__ ln2_w,
    const float* __restrict__ ln2_b,
    const float* __restrict__ attn_w,     // [8][38]
    const float* __restrict__ attn_b,     // [8]
    const float* __restrict__ clf_w,      // [8][38]
    const float* __restrict__ clf_b,      // [8]
    float* __restrict__ out_logits,       // [B][8]
    float* __restrict__ out_scores)       // [B][8][64]
{
    const int b = blockIdx.x;
    const int tid = threadIdx.x;

    __shared__ float s_x[L*D];        // 2432 floats
    __shared__ float s_qkv[L*QKV];    // 7296 floats (reused as FFN intermediate)
    __shared__ float s_att[L*L];      // 4096 floats (reused as tmp [64][38] and scores)
    __shared__ float s_a[L*D];        // 2432 floats

    // ---- load x[b] ----
    const float* xb = x_g + (size_t)b * (L*D);
    for (int i = tid; i < L*D; i += BDIM) s_x[i] = xb[i];
    __syncthreads();

    const float scale = rsqrtf((float)HD);

    for (int layer = 0; layer < NL; ++layer) {
        const float* Wqkv = in_proj_w + layer*QKV*D;
        const float* bqkv = in_proj_b + layer*QKV;

        // ---- QKV projection: s_qkv[row][col] ----
        for (int idx = tid; idx < L*QKV; idx += BDIM) {
            int row = idx / QKV, col = idx - row*QKV;
            const float* w  = Wqkv + col*D;
            const float* xr = s_x + row*D;
            float acc = bqkv[col];
            #pragma unroll
            for (int k = 0; k < D; ++k) acc = fmaf(xr[k], w[k], acc);
            s_qkv[idx] = acc;
        }
        __syncthreads();

        // ---- attention, head by head ----
        for (int h = 0; h < H; ++h) {
            // att[l][m] = scale * dot(q[l,h], k[m,h])
            for (int idx = tid; idx < L*L; idx += BDIM) {
                int l = idx >> 6, m = idx & 63;
                const float* qr = s_qkv + l*QKV + h*HD;
                const float* kr = s_qkv + m*QKV + D + h*HD;
                float acc = 0.f;
                #pragma unroll
                for (int d = 0; d < HD; ++d) acc = fmaf(qr[d], kr[d], acc);
                s_att[idx] = acc * scale;
            }
            __syncthreads();
            // row softmax (serial per row, 64 rows)
            if (tid < L) {
                float* row = s_att + tid*L;
                float mx = row[0];
                for (int m = 1; m < L; ++m) mx = fmaxf(mx, row[m]);
                float sum = 0.f;
                for (int m = 0; m < L; ++m) { float e = expf(row[m]-mx); row[m] = e; sum += e; }
                float inv = 1.f/sum;
                for (int m = 0; m < L; ++m) row[m] *= inv;
            }
            __syncthreads();
            // a[l][h*19+d] = sum_m att[l][m] * v[m][h*19+d]
            for (int idx = tid; idx < L*HD; idx += BDIM) {
                int l = idx / HD, d = idx - l*HD;
                const float* ar = s_att + l*L;
                float acc = 0.f;
                #pragma unroll 8
                for (int m = 0; m < L; ++m) acc = fmaf(ar[m], s_qkv[m*QKV + 2*D + h*HD + d], acc);
                s_a[l*D + h*HD + d] = acc;
            }
            __syncthreads();
        }

        // ---- out proj + residual -> s_att[0:64*38] ----
        const float* Wo = out_w + layer*D*D;
        const float* bo = out_b + layer*D;
        for (int idx = tid; idx < L*D; idx += BDIM) {
            int row = idx / D, col = idx - row*D;
            const float* w  = Wo + col*D;
            const float* ar = s_a + row*D;
            float acc = bo[col];
            #pragma unroll
            for (int k = 0; k < D; ++k) acc = fmaf(ar[k], w[k], acc);
            s_att[idx] = acc + s_x[idx];
        }
        __syncthreads();

        // ---- LN1 -> s_x ----
        {
            const float* g = ln1_w + layer*D;
            const float* be = ln1_b + layer*D;
            if (tid < L) {
                const float* r = s_att + tid*D;
                float mu = 0.f;
                for (int k = 0; k < D; ++k) mu += r[k];
                mu *= (1.f/D);
                float var = 0.f;
                for (int k = 0; k < D; ++k) { float dv = r[k]-mu; var = fmaf(dv, dv, var); }
                var *= (1.f/D);
                float inv = rsqrtf(var + 1e-5f);
                for (int k = 0; k < D; ++k) s_x[tid*D+k] = (r[k]-mu)*inv*g[k] + be[k];
            }
        }
        __syncthreads();

        // ---- FFN1 + exact GELU -> s_qkv[0:64*38] ----
        const float* W1 = lin1_w + layer*D*D;
        const float* b1 = lin1_b + layer*D;
        for (int idx = tid; idx < L*D; idx += BDIM) {
            int row = idx / D, col = idx - row*D;
            const float* w  = W1 + col*D;
            const float* xr = s_x + row*D;
            float acc = b1[col];
            #pragma unroll
            for (int k = 0; k < D; ++k) acc = fmaf(xr[k], w[k], acc);
            float g = 0.5f*acc*(1.0f + erff(acc*0.70710678118654752f));
            s_qkv[idx] = g;
        }
        __syncthreads();

        // ---- FFN2 + residual -> s_att ----
        const float* W2 = lin2_w + layer*D*D;
        const float* b2 = lin2_b + layer*D;
        for (int idx = tid; idx < L*D; idx += BDIM) {
            int row = idx / D, col = idx - row*D;
            const float* w  = W2 + col*D;
            const float* fr = s_qkv + row*D;
            float acc = b2[col];
            #pragma unroll
            for (int k = 0; k < D; ++k) acc = fmaf(fr[k], w[k], acc);
            s_att[idx] = acc + s_x[idx];
        }
        __syncthreads();

        // ---- LN2 -> s_x ----
        {
            const float* g = ln2_w + layer*D;
            const float* be = ln2_b + layer*D;
            if (tid < L) {
                const float* r = s_att + tid*D;
                float mu = 0.f;
                for (int k = 0; k < D; ++k) mu += r[k];
                mu *= (1.f/D);
                float var = 0.f;
                for (int k = 0; k < D; ++k) { float dv = r[k]-mu; var = fmaf(dv, dv, var); }
                var *= (1.f/D);
                float inv = rsqrtf(var + 1e-5f);
                for (int k = 0; k < D; ++k) s_x[tid*D+k] = (r[k]-mu)*inv*g[k] + be[k];
            }
        }
        __syncthreads();
    }

    // ---- pooling: sc[k][l] = dot(x[l], attn_w[k]) + attn_b[k] ----
    for (int idx = tid; idx < KD*L; idx += BDIM) {
        int k = idx >> 6, l = idx & 63;
        const float* w  = attn_w + k*D;
        const float* xr = s_x + l*D;
        float acc = attn_b[k];
        #pragma unroll
        for (int d = 0; d < D; ++d) acc = fmaf(xr[d], w[d], acc);
        s_att[idx] = acc;
    }
    __syncthreads();
    // softmax over l per k (8 rows)
    if (tid < KD) {
        float* row = s_att + tid*L;
        float mx = row[0];
        for (int m = 1; m < L; ++m) mx = fmaxf(mx, row[m]);
        float sum = 0.f;
        for (int m = 0; m < L; ++m) { float e = expf(row[m]-mx); row[m] = e; sum += e; }
        float inv = 1.f/sum;
        for (int m = 0; m < L; ++m) row[m] *= inv;
    }
    __syncthreads();

    // write scores [8][64]
    float* sc_out = out_scores + (size_t)b * (KD*L);
    for (int i = tid; i < KD*L; i += BDIM) sc_out[i] = s_att[i];

    // feats[k][d] * clf_w[k][d] -> s_a
    for (int idx = tid; idx < KD*D; idx += BDIM) {
        int k = idx / D, d = idx - k*D;
        float acc = 0.f;
        #pragma unroll 8
        for (int l = 0; l < L; ++l) acc = fmaf(s_att[k*L + l], s_x[l*D + d], acc);
        s_a[idx] = acc * clf_w[k*D + d];
    }
    __syncthreads();
    if (tid < KD) {
        float acc = clf_b[tid];
        #pragma unroll
        for (int d = 0; d < D; ++d) acc += s_a[tid*D + d];
        out_logits[(size_t)b*KD + tid] = acc;
    }
}

extern "C" void kernel_launch(void* const* d_in, const int* in_sizes, int n_in,
                              void* d_out, int out_size, void* d_ws, size_t ws_size,
                              hipStream_t stream) {
    const float* x         = (const float*)d_in[0];
    const float* in_proj_w = (const float*)d_in[1];
    const float* in_proj_b = (const float*)d_in[2];
    const float* out_w     = (const float*)d_in[3];
    const float* out_b     = (const float*)d_in[4];
    const float* lin1_w    = (const float*)d_in[5];
    const float* lin1_b    = (const float*)d_in[6];
    const float* lin2_w    = (const float*)d_in[7];
    const float* lin2_b    = (const float*)d_in[8];
    const float* ln1_w     = (const float*)d_in[9];
    const float* ln1_b     = (const float*)d_in[10];
    const float* ln2_w     = (const float*)d_in[11];
    const float* ln2_b     = (const float*)d_in[12];
    const float* attn_w    = (const float*)d_in[13];
    const float* attn_b    = (const float*)d_in[14];
    const float* clf_w     = (const float*)d_in[15];
    const float* clf_b     = (const float*)d_in[16];

    const int B = in_sizes[0] / (L*D);           // 8192
    float* out_logits = (float*)d_out;           // [B][8]
    float* out_scores = out_logits + (size_t)B*KD; // [B][8][64]

    symptom_fused_kernel<<<B, BDIM, 0, stream>>>(
        x, in_proj_w, in_proj_b, out_w, out_b, lin1_w, lin1_b, lin2_w, lin2_b,
        ln1_w, ln1_b, ln2_w, ln2_b, attn_w, attn_b, clf_w, clf_b,
        out_logits, out_scores);
}

// Round 2
// 3124.356 us; speedup vs baseline: 2.4808x; 2.4808x over previous
//
#include <hip/hip_runtime.h>
#include <math.h>

#define BDIM 256
#define L 64
#define D 38
#define H 2
#define HD 19
#define NL 6
#define KD 8
#define QKV 114

__device__ __forceinline__ float rl(float v, int m) {
    return __uint_as_float(__builtin_amdgcn_readlane(__float_as_uint(v), m));
}

__global__ __launch_bounds__(BDIM, 2) void symptom_fused_kernel(
    const float* __restrict__ x_g,
    const float* __restrict__ in_proj_w,  // [NL][114][38]
    const float* __restrict__ in_proj_b,  // [NL][114]
    const float* __restrict__ out_w,      // [NL][38][38]
    const float* __restrict__ out_b,      // [NL][38]
    const float* __restrict__ lin1_w,     // [NL][38][38]
    const float* __restrict__ lin1_b,     // [NL][38]
    const float* __restrict__ lin2_w,     // [NL][38][38]
    const float* __restrict__ lin2_b,     // [NL][38]
    const float* __restrict__ ln1_w,      // [NL][38]
    const float* __restrict__ ln1_b,
    const float* __restrict__ ln2_w,
    const float* __restrict__ ln2_b,
    const float* __restrict__ attn_w,     // [8][38]
    const float* __restrict__ attn_b,     // [8]
    const float* __restrict__ clf_w,      // [8][38]
    const float* __restrict__ clf_b,      // [8]
    float* __restrict__ out_logits,       // [B][8]
    float* __restrict__ out_scores)       // [B][8][64]
{
    const int b    = blockIdx.x;
    const int tid  = threadIdx.x;
    const int lane = tid & 63;
    const int wid  = __builtin_amdgcn_readfirstlane(tid >> 6);  // SGPR-uniform wave id

    __shared__ __align__(16) float s_x[L*D];      // 2432 (activation, in-place residual/LN)
    __shared__ __align__(16) float s_qkv[L*QKV];  // 7296 (q|k|v; q-region reused for attn out)
    __shared__ __align__(16) float s_ap[4*L*HD];  // 4864 (per-wave AV partials; f-buffer in FFN)
    __shared__ __align__(16) float s_red[512];    // softmax cross-wave partials

    // ---- load x[b] ----
    const float* xb = x_g + (size_t)b * (L*D);
    for (int i = tid; i < L*D; i += BDIM) s_x[i] = xb[i];
    __syncthreads();

    const float scale = 0.22941573387056174f;  // 1/sqrt(19)

    for (int layer = 0; layer < NL; ++layer) {
        // ================= QKV projection =================
        {
            const float* Wl = in_proj_w + layer*QKV*D;
            const float* bl = in_proj_b + layer*QKV;
            float xr[D];
            const float2* xp = reinterpret_cast<const float2*>(s_x + lane*D);
            #pragma unroll
            for (int k = 0; k < D/2; ++k) { float2 t = xp[k]; xr[2*k]=t.x; xr[2*k+1]=t.y; }
            for (int c = wid; c < QKV; c += 4) {   // uniform c -> weights via s_load
                const float* w = Wl + c*D;
                float acc = bl[c];
                #pragma unroll
                for (int k = 0; k < D; ++k) acc = fmaf(xr[k], w[k], acc);
                s_qkv[lane*QKV + c] = acc;
            }
        }
        __syncthreads();

        // ================= attention (per head) =================
        for (int h = 0; h < H; ++h) {
            // q,k rows into regs (lane = row)
            float q[HD], k[HD];
            {
                const float* qp = s_qkv + lane*QKV + h*HD;
                const float* kp = s_qkv + lane*QKV + D + h*HD;
                #pragma unroll
                for (int d = 0; d < HD; ++d) { q[d]=qp[d]; k[d]=kp[d]; }
            }
            // att[lane][m] for m in this wave's quarter, k broadcast via readlane
            float p[16];
            #pragma unroll
            for (int j = 0; j < 16; ++j) {
                const int m = wid*16 + j;
                float acc = 0.f;
                #pragma unroll
                for (int d = 0; d < HD; ++d) acc = fmaf(rl(k[d], m), q[d], acc);
                p[j] = acc * scale;
            }
            // softmax across the 4 m-quarters (cross-wave via s_red)
            float pmax = p[0];
            #pragma unroll
            for (int j = 1; j < 16; ++j) pmax = fmaxf(pmax, p[j]);
            s_red[lane*4 + wid] = pmax;
            __syncthreads();
            float4 m4 = reinterpret_cast<const float4*>(s_red)[lane];
            float gmax = fmaxf(fmaxf(m4.x, m4.y), fmaxf(m4.z, m4.w));
            float psum = 0.f;
            #pragma unroll
            for (int j = 0; j < 16; ++j) { p[j] = __expf(p[j]-gmax); psum += p[j]; }
            s_red[256 + lane*4 + wid] = psum;
            __syncthreads();
            float4 s4 = reinterpret_cast<const float4*>(s_red + 256)[lane];
            float inv = 1.f/(s4.x + s4.y + s4.z + s4.w);
            #pragma unroll
            for (int j = 0; j < 16; ++j) p[j] *= inv;

            // AV: partial over this wave's m-quarter, v broadcast via readlane
            float v[HD], a[HD];
            {
                const float* vp = s_qkv + lane*QKV + 2*D + h*HD;
                #pragma unroll
                for (int d = 0; d < HD; ++d) { v[d]=vp[d]; a[d]=0.f; }
            }
            #pragma unroll
            for (int j = 0; j < 16; ++j) {
                const int m = wid*16 + j;
                #pragma unroll
                for (int d = 0; d < HD; ++d) a[d] = fmaf(rl(v[d], m), p[j], a[d]);
            }
            {
                float* ap = s_ap + wid*(L*HD) + lane*HD;   // stride 19: conflict-free
                #pragma unroll
                for (int d = 0; d < HD; ++d) ap[d] = a[d];
            }
            __syncthreads();
            // reduce 4 partials -> attn out into q-region cols [h*19, h*19+19)
            for (int idx = tid; idx < L*HD; idx += BDIM) {
                float s = s_ap[idx] + s_ap[L*HD + idx] + s_ap[2*L*HD + idx] + s_ap[3*L*HD + idx];
                int l = idx / HD, d = idx - l*HD;
                s_qkv[l*QKV + h*HD + d] = s;
            }
            // next head's softmax barriers order s_ap/s_qkv reuse safely
        }
        __syncthreads();

        // ================= out-proj + residual (in-place s_x) =================
        {
            const float* Wl = out_w + layer*D*D;
            const float* bl = out_b + layer*D;
            float ar[D];
            const float2* ap2 = reinterpret_cast<const float2*>(s_qkv + lane*QKV);
            #pragma unroll
            for (int kk = 0; kk < D/2; ++kk) { float2 t = ap2[kk]; ar[2*kk]=t.x; ar[2*kk+1]=t.y; }
            for (int c = wid; c < D; c += 4) {
                const float* w = Wl + c*D;
                float acc = bl[c];
                #pragma unroll
                for (int k = 0; k < D; ++k) acc = fmaf(ar[k], w[k], acc);
                s_x[lane*D + c] += acc;
            }
        }
        __syncthreads();

        // ================= LN1 (in-place, 4 lanes per row) =================
        {
            const float* g  = ln1_w + layer*D;
            const float* be = ln1_b + layer*D;
            const int row = wid*16 + (lane >> 2);
            const int j   = lane & 3;
            float loc[10]; float sum = 0.f, ssq = 0.f;
            #pragma unroll
            for (int kk = 0; kk < 10; ++kk) {
                int k = j*10 + kk;
                float vv = (k < D) ? s_x[row*D + k] : 0.f;
                loc[kk] = vv; sum += vv; ssq = fmaf(vv, vv, ssq);
            }
            sum += __shfl_xor(sum, 1); sum += __shfl_xor(sum, 2);
            ssq += __shfl_xor(ssq, 1); ssq += __shfl_xor(ssq, 2);
            float mu   = sum * (1.f/D);
            float var  = ssq * (1.f/D) - mu*mu;
            float invs = rsqrtf(var + 1e-5f);
            #pragma unroll
            for (int kk = 0; kk < 10; ++kk) {
                int k = j*10 + kk;
                if (k < D) s_x[row*D + k] = (loc[kk]-mu)*invs*g[k] + be[k];
            }
        }
        __syncthreads();

        // ================= FFN1 + exact GELU -> s_ap =================
        {
            const float* Wl = lin1_w + layer*D*D;
            const float* bl = lin1_b + layer*D;
            float xr[D];
            const float2* xp = reinterpret_cast<const float2*>(s_x + lane*D);
            #pragma unroll
            for (int k = 0; k < D/2; ++k) { float2 t = xp[k]; xr[2*k]=t.x; xr[2*k+1]=t.y; }
            for (int c = wid; c < D; c += 4) {
                const float* w = Wl + c*D;
                float acc = bl[c];
                #pragma unroll
                for (int k = 0; k < D; ++k) acc = fmaf(xr[k], w[k], acc);
                s_ap[lane*D + c] = 0.5f*acc*(1.0f + erff(acc*0.70710678118654752f));
            }
        }
        __syncthreads();

        // ================= FFN2 + residual (in-place s_x) =================
        {
            const float* Wl = lin2_w + layer*D*D;
            const float* bl = lin2_b + layer*D;
            float fr[D];
            const float2* fp = reinterpret_cast<const float2*>(s_ap + lane*D);
            #pragma unroll
            for (int kk = 0; kk < D/2; ++kk) { float2 t = fp[kk]; fr[2*kk]=t.x; fr[2*kk+1]=t.y; }
            for (int c = wid; c < D; c += 4) {
                const float* w = Wl + c*D;
                float acc = bl[c];
                #pragma unroll
                for (int k = 0; k < D; ++k) acc = fmaf(fr[k], w[k], acc);
                s_x[lane*D + c] += acc;
            }
        }
        __syncthreads();

        // ================= LN2 (in-place) =================
        {
            const float* g  = ln2_w + layer*D;
            const float* be = ln2_b + layer*D;
            const int row = wid*16 + (lane >> 2);
            const int j   = lane & 3;
            float loc[10]; float sum = 0.f, ssq = 0.f;
            #pragma unroll
            for (int kk = 0; kk < 10; ++kk) {
                int k = j*10 + kk;
                float vv = (k < D) ? s_x[row*D + k] : 0.f;
                loc[kk] = vv; sum += vv; ssq = fmaf(vv, vv, ssq);
            }
            sum += __shfl_xor(sum, 1); sum += __shfl_xor(sum, 2);
            ssq += __shfl_xor(ssq, 1); ssq += __shfl_xor(ssq, 2);
            float mu   = sum * (1.f/D);
            float var  = ssq * (1.f/D) - mu*mu;
            float invs = rsqrtf(var + 1e-5f);
            #pragma unroll
            for (int kk = 0; kk < 10; ++kk) {
                int k = j*10 + kk;
                if (k < D) s_x[row*D + k] = (loc[kk]-mu)*invs*g[k] + be[k];
            }
        }
        __syncthreads();
    }

    // ================= pooling + classifier =================
    {
        float xr[D];
        const float2* xp = reinterpret_cast<const float2*>(s_x + lane*D);
        #pragma unroll
        for (int k = 0; k < D/2; ++k) { float2 t = xp[k]; xr[2*k]=t.x; xr[2*k+1]=t.y; }
        #pragma unroll
        for (int kk = 0; kk < 2; ++kk) {
            const int k = wid*2 + kk;                 // wave handles diseases 2w, 2w+1
            const float* aw = attn_w + k*D;
            float sc = attn_b[k];
            #pragma unroll
            for (int d = 0; d < D; ++d) sc = fmaf(xr[d], aw[d], sc);
            // softmax over 64 lanes
            float mx = sc;
            #pragma unroll
            for (int off = 32; off > 0; off >>= 1) mx = fmaxf(mx, __shfl_xor(mx, off));
            float e = __expf(sc - mx);
            float sm = e;
            #pragma unroll
            for (int off = 32; off > 0; off >>= 1) sm += __shfl_xor(sm, off);
            float pr = e / sm;
            out_scores[(size_t)b*(KD*L) + k*L + lane] = pr;
            // logits[k] = sum_l pr[l] * dot(x[l], clf_w[k]) + clf_b[k]
            const float* cw = clf_w + k*D;
            float y = 0.f;
            #pragma unroll
            for (int d = 0; d < D; ++d) y = fmaf(xr[d], cw[d], y);
            float t = pr * y;
            #pragma unroll
            for (int off = 32; off > 0; off >>= 1) t += __shfl_xor(t, off);
            if (lane == 0) out_logits[(size_t)b*KD + k] = t + clf_b[k];
        }
    }
}

extern "C" void kernel_launch(void* const* d_in, const int* in_sizes, int n_in,
                              void* d_out, int out_size, void* d_ws, size_t ws_size,
                              hipStream_t stream) {
    const float* x         = (const float*)d_in[0];
    const float* in_proj_w = (const float*)d_in[1];
    const float* in_proj_b = (const float*)d_in[2];
    const float* out_w     = (const float*)d_in[3];
    const float* out_b     = (const float*)d_in[4];
    const float* lin1_w    = (const float*)d_in[5];
    const float* lin1_b    = (const float*)d_in[6];
    const float* lin2_w    = (const float*)d_in[7];
    const float* lin2_b    = (const float*)d_in[8];
    const float* ln1_w     = (const float*)d_in[9];
    const float* ln1_b     = (const float*)d_in[10];
    const float* ln2_w     = (const float*)d_in[11];
    const float* ln2_b     = (const float*)d_in[12];
    const float* attn_w    = (const float*)d_in[13];
    const float* attn_b    = (const float*)d_in[14];
    const float* clf_w     = (const float*)d_in[15];
    const float* clf_b     = (const float*)d_in[16];

    const int B = in_sizes[0] / (L*D);             // 8192
    float* out_logits = (float*)d_out;             // [B][8]
    float* out_scores = out_logits + (size_t)B*KD; // [B][8][64]

    symptom_fused_kernel<<<B, BDIM, 0, stream>>>(
        x, in_proj_w, in_proj_b, out_w, out_b, lin1_w, lin1_b, lin2_w, lin2_b,
        ln1_w, ln1_b, ln2_w, ln2_b, attn_w, attn_b, clf_w, clf_b,
        out_logits, out_scores);
}

// Round 8
// 2903.481 us; speedup vs baseline: 2.6695x; 1.0761x over previous
//
#include <hip/hip_runtime.h>
#include <math.h>

#define L 64
#define D 38
#define HD 19
#define NL 6
#define KD 8
#define QKV 114
#define XSTR 136   // x_b / pa stride (bf16)

typedef __attribute__((ext_vector_type(8))) __bf16 bf16x8;
typedef __attribute__((ext_vector_type(4))) float f32x4;

#define MFMA(a,b,c) __builtin_amdgcn_mfma_f32_16x16x32_bf16(a,b,c,0,0,0)

__device__ __forceinline__ float rl(float v, int m) {
    return __uint_as_float(__builtin_amdgcn_readlane(__float_as_uint(v), m));
}

// ---- d_ws bf16 weight sections, K-stacked [Wh(38)|Wl(38)|Wh(38)|0] per row ----
#define WQKV_ELEMS (NL*128*128)
#define WSEC       (NL*48*128)
#define WOUT_OFF   (WQKV_ELEMS)
#define W1_OFF     (WOUT_OFF + WSEC)
#define W2_OFF     (W1_OFF + WSEC)
#define WTOT       (W2_OFF + WSEC)     // 208896 elems

__global__ __launch_bounds__(256) void convert_weights(
    const float* __restrict__ ipw, const float* __restrict__ ow,
    const float* __restrict__ l1w, const float* __restrict__ l2w,
    __bf16* __restrict__ ws)
{
    int idx = blockIdx.x*256 + threadIdx.x;
    if (idx >= WTOT) return;
    if (idx < WQKV_ELEMS) {
        int l = idx >> 14;
        int rem = idx & 16383;
        int r = rem >> 7, j = rem & 127;
        float v = 0.f; int jj = -1; bool lo = false;
        if (j < 38) jj = j;
        else if (j < 76) { jj = j - 38; lo = true; }
        else if (j < 114) jj = j - 76;
        if (r < 114 && jj >= 0) v = ipw[(l*114 + r)*38 + jj];
        __bf16 hi = (__bf16)v;
        ws[idx] = lo ? (__bf16)(v - (float)hi) : hi;
        return;
    }
    int j2 = idx - WQKV_ELEMS;
    const float* src; int base;
    if      (j2 < WSEC)   { src = ow;  base = WOUT_OFF; }
    else if (j2 < 2*WSEC) { src = l1w; base = W1_OFF;  j2 -= WSEC; }
    else                  { src = l2w; base = W2_OFF;  j2 -= 2*WSEC; }
    int l = j2 / 6144;
    int rem = j2 - l*6144;
    int r = rem >> 7, j = rem & 127;
    float v = 0.f; int jj = -1; bool lo = false;
    if (j < 38) jj = j;
    else if (j < 76) { jj = j - 38; lo = true; }
    else if (j < 114) jj = j - 76;
    if (r < 38 && jj >= 0) v = src[(l*38 + r)*38 + jj];
    __bf16 hi = (__bf16)v;
    ws[base + j2] = lo ? (__bf16)(v - (float)hi) : hi;
}

__global__ __launch_bounds__(256, 2) void symptom_hybrid(
    const float* __restrict__ x_g,
    const float* __restrict__ in_proj_b,
    const float* __restrict__ out_b,
    const float* __restrict__ lin1_b,
    const float* __restrict__ lin2_b,
    const float* __restrict__ ln1_w, const float* __restrict__ ln1_b,
    const float* __restrict__ ln2_w, const float* __restrict__ ln2_b,
    const float* __restrict__ attn_w, const float* __restrict__ attn_b,
    const float* __restrict__ clf_w,  const float* __restrict__ clf_b,
    const __bf16* __restrict__ wsb,
    float* __restrict__ out_logits,   // [B][8]
    float* __restrict__ out_scores)   // [B][8][64]
{
    const int b    = blockIdx.x;
    const int tid  = threadIdx.x;
    const int lane = tid & 63;
    const int wid  = __builtin_amdgcn_readfirstlane(tid >> 6);
    const int lg   = lane >> 4;
    const int lm   = lane & 15;
    const int r0   = wid * 16;
    const int arow = r0 + lm;

    __shared__ __align__(16) float  s_qkv[L*QKV];   // fp32 q|k|v; attn-out a in q-region  29184 B
    __shared__ __align__(16) __bf16 x_b[L*XSTR];    // stacked x [xh|xh|xl|0]              17408 B
    __shared__ __align__(16) float  x32[L*D];       // fp32 residual                        9728 B
    __shared__ __align__(16) char   u_buf[4*L*HD*4];// s_ap fp32 / pa bf16 (stacked a,f)   19456 B
    __shared__ __align__(16) float  s_red[512];     //                                      2048 B
    float*  s_ap = (float*)u_buf;
    __bf16* pa   = (__bf16*)u_buf;

    // ---- stage x: fp32 + stacked bf16 hi/lo; zero x_b pads ----
    const float* xb = x_g + (size_t)b*(L*D);
    for (int i = tid; i < L*D; i += 256) {
        float v = xb[i];
        int r = i / D, c = i - r*D;
        x32[i] = v;
        __bf16 hi = (__bf16)v;
        x_b[r*XSTR + c]      = hi;
        x_b[r*XSTR + 38 + c] = hi;
        x_b[r*XSTR + 76 + c] = (__bf16)(v - (float)hi);
    }
    for (int i = tid; i < L*14; i += 256) {
        int r = i / 14, c = i - r*14;
        x_b[r*XSTR + 114 + c] = (__bf16)0.f;
    }
    __syncthreads();

    const float scale = 0.22941573387056174f;  // 1/sqrt(19)

    for (int layer = 0; layer < NL; ++layer) {
        // ============ QKV projection: compensated MFMA -> fp32 s_qkv ============
        {
            const __bf16* xr = &x_b[arow*XSTR];
            bf16x8 a0 = *(const bf16x8*)(xr + lg*8);
            bf16x8 a1 = *(const bf16x8*)(xr + 32 + lg*8);
            bf16x8 a2 = *(const bf16x8*)(xr + 64 + lg*8);
            bf16x8 a3 = *(const bf16x8*)(xr + 96 + lg*8);
            const __bf16* wl = wsb + layer*(128*128);
            #pragma unroll
            for (int n = 0; n < 8; ++n) {
                const __bf16* wp = wl + (n*16 + lm)*128;
                f32x4 acc = {0.f,0.f,0.f,0.f};
                acc = MFMA(a0, *(const bf16x8*)(wp + lg*8),      acc);
                acc = MFMA(a1, *(const bf16x8*)(wp + 32 + lg*8), acc);
                acc = MFMA(a2, *(const bf16x8*)(wp + 64 + lg*8), acc);
                acc = MFMA(a3, *(const bf16x8*)(wp + 96 + lg*8), acc);
                int c = n*16 + lm;
                if (c < QKV) {
                    float bias = in_proj_b[layer*QKV + c];
                    #pragma unroll
                    for (int i = 0; i < 4; ++i)
                        s_qkv[(r0 + lg*4 + i)*QKV + c] = acc[i] + bias;
                }
            }
        }
        __syncthreads();   // BAR1: full fp32 qkv visible

        // ============ attention: R2-verbatim fp32 VALU ============
        for (int h = 0; h < 2; ++h) {
            float q[HD], k[HD];
            {
                const float* qp = s_qkv + lane*QKV + h*HD;
                const float* kp = s_qkv + lane*QKV + D + h*HD;
                #pragma unroll
                for (int d = 0; d < HD; ++d) { q[d]=qp[d]; k[d]=kp[d]; }
            }
            float p[16];
            #pragma unroll
            for (int j = 0; j < 16; ++j) {
                const int m = wid*16 + j;
                float acc = 0.f;
                #pragma unroll
                for (int d = 0; d < HD; ++d) acc = fmaf(rl(k[d], m), q[d], acc);
                p[j] = acc * scale;
            }
            float pmax = p[0];
            #pragma unroll
            for (int j = 1; j < 16; ++j) pmax = fmaxf(pmax, p[j]);
            s_red[lane*4 + wid] = pmax;
            __syncthreads();
            float4 m4 = reinterpret_cast<const float4*>(s_red)[lane];
            float gmax = fmaxf(fmaxf(m4.x, m4.y), fmaxf(m4.z, m4.w));
            float psum = 0.f;
            #pragma unroll
            for (int j = 0; j < 16; ++j) { p[j] = __expf(p[j]-gmax); psum += p[j]; }
            s_red[256 + lane*4 + wid] = psum;
            __syncthreads();
            float4 s4 = reinterpret_cast<const float4*>(s_red + 256)[lane];
            float inv = 1.f/(s4.x + s4.y + s4.z + s4.w);
            #pragma unroll
            for (int j = 0; j < 16; ++j) p[j] *= inv;

            float v[HD], a[HD];
            {
                const float* vp = s_qkv + lane*QKV + 2*D + h*HD;
                #pragma unroll
                for (int d = 0; d < HD; ++d) { v[d]=vp[d]; a[d]=0.f; }
            }
            #pragma unroll
            for (int j = 0; j < 16; ++j) {
                const int m = wid*16 + j;
                #pragma unroll
                for (int d = 0; d < HD; ++d) a[d] = fmaf(rl(v[d], m), p[j], a[d]);
            }
            {
                float* ap = s_ap + wid*(L*HD) + lane*HD;
                #pragma unroll
                for (int d = 0; d < HD; ++d) ap[d] = a[d];
            }
            __syncthreads();
            for (int idx = tid; idx < L*HD; idx += 256) {
                float s = s_ap[idx] + s_ap[L*HD + idx] + s_ap[2*L*HD + idx] + s_ap[3*L*HD + idx];
                int l = idx / HD, d = idx - l*HD;
                s_qkv[l*QKV + h*HD + d] = s;
            }
            __syncthreads();   // a-slice visible; also protects s_ap reuse next head
        }

        // ---- stack a (own rows) from s_qkv fp32 -> pa [ah|ah|al|0] ----
        #pragma unroll
        for (int n = 0; n < 3; ++n) {
            const int c = n*16 + lm;
            if (c < 38) {
                #pragma unroll
                for (int i = 0; i < 4; ++i) {
                    int r = r0 + lg*4 + i;
                    float v = s_qkv[r*QKV + c];
                    __bf16 hi = (__bf16)v;
                    pa[r*XSTR + c]      = hi;
                    pa[r*XSTR + 38 + c] = hi;
                    pa[r*XSTR + 76 + c] = (__bf16)(v - (float)hi);
                }
            }
        }
        if (lm < 14) {
            #pragma unroll
            for (int i = 0; i < 4; ++i) pa[(r0+lg*4+i)*XSTR + 114 + lm] = (__bf16)0.f;
        }
        // (no barrier: out-proj reads own-wave rows, in-order LDS within wave)

        // ============ out-proj (compensated MFMA) + residual + LN1 ============
        {
            const __bf16* ar = &pa[arow*XSTR];
            bf16x8 a0 = *(const bf16x8*)(ar + lg*8);
            bf16x8 a1 = *(const bf16x8*)(ar + 32 + lg*8);
            bf16x8 a2 = *(const bf16x8*)(ar + 64 + lg*8);
            bf16x8 a3 = *(const bf16x8*)(ar + 96 + lg*8);
            const __bf16* wl = wsb + WOUT_OFF + layer*(48*128);
            f32x4 oo[3]; int c[3]; float bias[3], gw[3], gb[3];
            #pragma unroll
            for (int n = 0; n < 3; ++n) {
                const __bf16* wp = wl + (n*16 + lm)*128;
                f32x4 acc = {0.f,0.f,0.f,0.f};
                acc = MFMA(a0, *(const bf16x8*)(wp + lg*8),      acc);
                acc = MFMA(a1, *(const bf16x8*)(wp + 32 + lg*8), acc);
                acc = MFMA(a2, *(const bf16x8*)(wp + 64 + lg*8), acc);
                oo[n] = MFMA(a3, *(const bf16x8*)(wp + 96 + lg*8), acc);
                c[n] = n*16 + lm;
                bool val = c[n] < 38;
                bias[n] = val ? out_b[layer*38 + c[n]] : 0.f;
                gw[n]   = val ? ln1_w[layer*38 + c[n]] : 0.f;
                gb[n]   = val ? ln1_b[layer*38 + c[n]] : 0.f;
            }
            #pragma unroll
            for (int i = 0; i < 4; ++i) {
                int r = r0 + lg*4 + i;
                float t[3]; float sum = 0.f, ssq = 0.f;
                #pragma unroll
                for (int n = 0; n < 3; ++n) {
                    float v = 0.f;
                    if (c[n] < 38) v = x32[r*D + c[n]] + oo[n][i] + bias[n];
                    t[n] = v; sum += v; ssq += v*v;
                }
                sum += __shfl_xor(sum,1); sum += __shfl_xor(sum,2); sum += __shfl_xor(sum,4); sum += __shfl_xor(sum,8);
                ssq += __shfl_xor(ssq,1); ssq += __shfl_xor(ssq,2); ssq += __shfl_xor(ssq,4); ssq += __shfl_xor(ssq,8);
                float mu  = sum*(1.f/38.f);
                float var = ssq*(1.f/38.f) - mu*mu;
                float inv = rsqrtf(var + 1e-5f);
                #pragma unroll
                for (int n = 0; n < 3; ++n) if (c[n] < 38) {
                    float v = (t[n]-mu)*inv*gw[n] + gb[n];
                    x32[r*D + c[n]] = v;
                    __bf16 hi = (__bf16)v;
                    x_b[r*XSTR + c[n]]      = hi;
                    x_b[r*XSTR + 38 + c[n]] = hi;
                    x_b[r*XSTR + 76 + c[n]] = (__bf16)(v - (float)hi);
                }
            }
        }

        // ============ FFN1 (compensated MFMA) + exact GELU -> pa ============
        {
            const __bf16* xr = &x_b[arow*XSTR];
            bf16x8 a0 = *(const bf16x8*)(xr + lg*8);
            bf16x8 a1 = *(const bf16x8*)(xr + 32 + lg*8);
            bf16x8 a2 = *(const bf16x8*)(xr + 64 + lg*8);
            bf16x8 a3 = *(const bf16x8*)(xr + 96 + lg*8);
            const __bf16* wl = wsb + W1_OFF + layer*(48*128);
            #pragma unroll
            for (int n = 0; n < 3; ++n) {
                const __bf16* wp = wl + (n*16 + lm)*128;
                f32x4 acc = {0.f,0.f,0.f,0.f};
                acc = MFMA(a0, *(const bf16x8*)(wp + lg*8),      acc);
                acc = MFMA(a1, *(const bf16x8*)(wp + 32 + lg*8), acc);
                acc = MFMA(a2, *(const bf16x8*)(wp + 64 + lg*8), acc);
                acc = MFMA(a3, *(const bf16x8*)(wp + 96 + lg*8), acc);
                int c = n*16 + lm;
                if (c < 38) {
                    float bias = lin1_b[layer*38 + c];
                    #pragma unroll
                    for (int i = 0; i < 4; ++i) {
                        float v = acc[i] + bias;
                        v = 0.5f*v*(1.0f + erff(v*0.70710678118654752f));
                        __bf16 hi = (__bf16)v;
                        int r = r0 + lg*4 + i;
                        pa[r*XSTR + c]      = hi;
                        pa[r*XSTR + 38 + c] = hi;
                        pa[r*XSTR + 76 + c] = (__bf16)(v - (float)hi);
                    }
                }
            }
        }

        // ============ FFN2 (compensated MFMA) + residual + LN2 ============
        {
            const __bf16* fr = &pa[arow*XSTR];
            bf16x8 a0 = *(const bf16x8*)(fr + lg*8);
            bf16x8 a1 = *(const bf16x8*)(fr + 32 + lg*8);
            bf16x8 a2 = *(const bf16x8*)(fr + 64 + lg*8);
            bf16x8 a3 = *(const bf16x8*)(fr + 96 + lg*8);
            const __bf16* wl = wsb + W2_OFF + layer*(48*128);
            f32x4 oo[3]; int c[3]; float bias[3], gw[3], gb[3];
            #pragma unroll
            for (int n = 0; n < 3; ++n) {
                const __bf16* wp = wl + (n*16 + lm)*128;
                f32x4 acc = {0.f,0.f,0.f,0.f};
                acc = MFMA(a0, *(const bf16x8*)(wp + lg*8),      acc);
                acc = MFMA(a1, *(const bf16x8*)(wp + 32 + lg*8), acc);
                acc = MFMA(a2, *(const bf16x8*)(wp + 64 + lg*8), acc);
                oo[n] = MFMA(a3, *(const bf16x8*)(wp + 96 + lg*8), acc);
                c[n] = n*16 + lm;
                bool val = c[n] < 38;
                bias[n] = val ? lin2_b[layer*38 + c[n]] : 0.f;
                gw[n]   = val ? ln2_w[layer*38 + c[n]] : 0.f;
                gb[n]   = val ? ln2_b[layer*38 + c[n]] : 0.f;
            }
            #pragma unroll
            for (int i = 0; i < 4; ++i) {
                int r = r0 + lg*4 + i;
                float t[3]; float sum = 0.f, ssq = 0.f;
                #pragma unroll
                for (int n = 0; n < 3; ++n) {
                    float v = 0.f;
                    if (c[n] < 38) v = x32[r*D + c[n]] + oo[n][i] + bias[n];
                    t[n] = v; sum += v; ssq += v*v;
                }
                sum += __shfl_xor(sum,1); sum += __shfl_xor(sum,2); sum += __shfl_xor(sum,4); sum += __shfl_xor(sum,8);
                ssq += __shfl_xor(ssq,1); ssq += __shfl_xor(ssq,2); ssq += __shfl_xor(ssq,4); ssq += __shfl_xor(ssq,8);
                float mu  = sum*(1.f/38.f);
                float var = ssq*(1.f/38.f) - mu*mu;
                float inv = rsqrtf(var + 1e-5f);
                #pragma unroll
                for (int n = 0; n < 3; ++n) if (c[n] < 38) {
                    float v = (t[n]-mu)*inv*gw[n] + gb[n];
                    x32[r*D + c[n]] = v;
                    __bf16 hi = (__bf16)v;
                    x_b[r*XSTR + c[n]]      = hi;
                    x_b[r*XSTR + 38 + c[n]] = hi;
                    x_b[r*XSTR + 76 + c[n]] = (__bf16)(v - (float)hi);
                }
            }
        }
        __syncthreads();   // before next layer's QKV overwrites s_qkv / u_buf
    }

    // ============ pooling + classifier (fp32, from x32) ============
    {
        float xr[D];
        const float2* xp = reinterpret_cast<const float2*>(x32 + lane*D);
        #pragma unroll
        for (int k = 0; k < D/2; ++k) { float2 t = xp[k]; xr[2*k]=t.x; xr[2*k+1]=t.y; }
        #pragma unroll
        for (int kk = 0; kk < 2; ++kk) {
            const int k = wid*2 + kk;
            const float* aw = attn_w + k*D;
            float sc = attn_b[k];
            #pragma unroll
            for (int d = 0; d < D; ++d) sc = fmaf(xr[d], aw[d], sc);
            float mx = sc;
            #pragma unroll
            for (int off = 32; off > 0; off >>= 1) mx = fmaxf(mx, __shfl_xor(mx, off));
            float e = __expf(sc - mx);
            float sm = e;
            #pragma unroll
            for (int off = 32; off > 0; off >>= 1) sm += __shfl_xor(sm, off);
            float pr = e / sm;
            out_scores[(size_t)b*(KD*L) + k*L + lane] = pr;
            const float* cw = clf_w + k*D;
            float y = 0.f;
            #pragma unroll
            for (int d = 0; d < D; ++d) y = fmaf(xr[d], cw[d], y);
            float t = pr * y;
            #pragma unroll
            for (int off = 32; off > 0; off >>= 1) t += __shfl_xor(t, off);
            if (lane == 0) out_logits[(size_t)b*KD + k] = t + clf_b[k];
        }
    }
}

extern "C" void kernel_launch(void* const* d_in, const int* in_sizes, int n_in,
                              void* d_out, int out_size, void* d_ws, size_t ws_size,
                              hipStream_t stream) {
    const float* x         = (const float*)d_in[0];
    const float* in_proj_w = (const float*)d_in[1];
    const float* in_proj_b = (const float*)d_in[2];
    const float* out_w     = (const float*)d_in[3];
    const float* out_b     = (const float*)d_in[4];
    const float* lin1_w    = (const float*)d_in[5];
    const float* lin1_b    = (const float*)d_in[6];
    const float* lin2_w    = (const float*)d_in[7];
    const float* lin2_b    = (const float*)d_in[8];
    const float* ln1_w     = (const float*)d_in[9];
    const float* ln1_b     = (const float*)d_in[10];
    const float* ln2_w     = (const float*)d_in[11];
    const float* ln2_b     = (const float*)d_in[12];
    const float* attn_w    = (const float*)d_in[13];
    const float* attn_b    = (const float*)d_in[14];
    const float* clf_w     = (const float*)d_in[15];
    const float* clf_b     = (const float*)d_in[16];

    const int B = in_sizes[0] / (L*D);             // 8192
    float* out_logits = (float*)d_out;             // [B][8]
    float* out_scores = out_logits + (size_t)B*KD; // [B][8][64]
    __bf16* wsb = (__bf16*)d_ws;

    convert_weights<<<(WTOT + 255)/256, 256, 0, stream>>>(in_proj_w, out_w, lin1_w, lin2_w, wsb);
    symptom_hybrid<<<B, 256, 0, stream>>>(
        x, in_proj_b, out_b, lin1_b, lin2_b,
        ln1_w, ln1_b, ln2_w, ln2_b, attn_w, attn_b, clf_w, clf_b,
        wsb, out_logits, out_scores);
}

// Round 16
// 2235.195 us; speedup vs baseline: 3.4677x; 1.2990x over previous
//
#include <hip/hip_runtime.h>
#include <math.h>

#define L 64
#define D 38
#define HD 19
#define NL 6
#define KD 8
#define QKV 114
#define XS 40      // s_x / s_q / s_f / s_vR row stride (160B, 16B-aligned)
#define KS 68      // s_kT row stride (272B, 16B-aligned)

__device__ __forceinline__ void load_row38(const float* __restrict__ row, float* r) {
    #pragma unroll
    for (int q4 = 0; q4 < 9; ++q4) {
        float4 t = *(const float4*)(row + q4*4);
        r[q4*4] = t.x; r[q4*4+1] = t.y; r[q4*4+2] = t.z; r[q4*4+3] = t.w;
    }
    r[36] = row[36]; r[37] = row[37];
}

__global__ __launch_bounds__(256, 3) void symptom_v16(
    const float* __restrict__ x_g,
    const float* __restrict__ ipw, const float* __restrict__ ipb,
    const float* __restrict__ ow,  const float* __restrict__ ob,
    const float* __restrict__ l1w, const float* __restrict__ l1b,
    const float* __restrict__ l2w, const float* __restrict__ l2b,
    const float* __restrict__ ln1w, const float* __restrict__ ln1b,
    const float* __restrict__ ln2w, const float* __restrict__ ln2b,
    const float* __restrict__ attn_w, const float* __restrict__ attn_b,
    const float* __restrict__ clf_w,  const float* __restrict__ clf_b,
    float* __restrict__ out_logits,   // [B][8]
    float* __restrict__ out_scores)   // [B][8][64]
{
    const int b    = blockIdx.x;
    const int tid  = threadIdx.x;
    const int lane = tid & 63;                                  // row index
    const int wid  = __builtin_amdgcn_readfirstlane(tid >> 6);  // wave id (col stripe)

    __shared__ __align__(16) float s_x[L*XS];    // 10240 B  activation (fp32)
    __shared__ __align__(16) float s_q[L*XS];    // 10240 B  q cols 0..37 / attn-out a
    __shared__ __align__(16) float s_red[512];   //  2048 B  cross-wave exchange
    __shared__ __align__(16) float U[7576];      // 30304 B  kT|vR|ap  (f overlays)
    float* s_kT = U;            // 38*68  = 2584 floats : kT[d][m]
    float* s_vR = U + 2584;     // 64*40  = 2560 floats : v rows (h0 at 0..18, h1 at 20..38)
    float* s_ap = U + 5144;     // 2*64*19= 2432 floats : PV partials (2-buffer)
    float* s_f  = U;            // 64*40 overlay: FFN intermediate
    // total LDS = 52832 B -> 3 blocks/CU

    // ---- stage x ----
    const float* xb = x_g + (size_t)b*(L*D);
    for (int i = tid; i < L*D; i += 256) {
        int r = i / D, c = i - r*D;
        s_x[r*XS + c] = xb[i];
    }
    for (int i = tid; i < L*2; i += 256) s_x[(i>>1)*XS + 38 + (i&1)] = 0.f;  // clean tail
    __syncthreads();

    const float scale = 0.22941573387056174f;   // 1/sqrt(19)

    for (int layer = 0; layer < NL; ++layer) {
        // ============ QKV projection (fp32, SGPR weights) ============
        {
            float xr[D];
            load_row38(s_x + lane*XS, xr);
            for (int c = wid; c < QKV; c += 4) {          // c wave-uniform
                const float* w = ipw + ((size_t)layer*QKV + c)*D;
                float acc = ipb[layer*QKV + c];
                #pragma unroll
                for (int k = 0; k < D; ++k) acc = fmaf(xr[k], w[k], acc);
                if (c < 38)      s_q[lane*XS + c] = acc;
                else if (c < 76) s_kT[(c-38)*KS + lane] = acc;
                else { int vv = c - 76; s_vR[lane*XS + vv + (vv >= 19 ? 1 : 0)] = acc; }
            }
        }
        __syncthreads();   // BAR: q/kT/vR ready

        // ============ attention (fp32, LDS-broadcast operands) ============
        for (int h = 0; h < 2; ++h) {
            float q[HD];
            {
                const float* qp = s_q + lane*XS + h*HD;
                #pragma unroll
                for (int d = 0; d < HD; ++d) q[d] = qp[d];
            }
            // S: p[j] over this wave's m-quarter
            float p[16];
            #pragma unroll
            for (int j = 0; j < 16; ++j) p[j] = 0.f;
            #pragma unroll
            for (int d = 0; d < HD; ++d) {
                const float* kp = s_kT + (h*HD + d)*KS + wid*16;   // wave-uniform
                float4 k0 = *(const float4*)(kp);
                float4 k1 = *(const float4*)(kp + 4);
                float4 k2 = *(const float4*)(kp + 8);
                float4 k3 = *(const float4*)(kp + 12);
                p[0]=fmaf(k0.x,q[d],p[0]); p[1]=fmaf(k0.y,q[d],p[1]); p[2]=fmaf(k0.z,q[d],p[2]); p[3]=fmaf(k0.w,q[d],p[3]);
                p[4]=fmaf(k1.x,q[d],p[4]); p[5]=fmaf(k1.y,q[d],p[5]); p[6]=fmaf(k1.z,q[d],p[6]); p[7]=fmaf(k1.w,q[d],p[7]);
                p[8]=fmaf(k2.x,q[d],p[8]); p[9]=fmaf(k2.y,q[d],p[9]); p[10]=fmaf(k2.z,q[d],p[10]); p[11]=fmaf(k2.w,q[d],p[11]);
                p[12]=fmaf(k3.x,q[d],p[12]); p[13]=fmaf(k3.y,q[d],p[13]); p[14]=fmaf(k3.z,q[d],p[14]); p[15]=fmaf(k3.w,q[d],p[15]);
            }
            #pragma unroll
            for (int j = 0; j < 16; ++j) p[j] *= scale;
            // softmax across the 4 m-quarters (two-barrier exchange)
            float pmax = p[0];
            #pragma unroll
            for (int j = 1; j < 16; ++j) pmax = fmaxf(pmax, p[j]);
            s_red[lane*4 + wid] = pmax;
            __syncthreads();
            float4 m4 = ((const float4*)s_red)[lane];
            float gmax = fmaxf(fmaxf(m4.x, m4.y), fmaxf(m4.z, m4.w));
            float psum = 0.f;
            #pragma unroll
            for (int j = 0; j < 16; ++j) { p[j] = __expf(p[j]-gmax); psum += p[j]; }
            s_red[256 + lane*4 + wid] = psum;
            __syncthreads();
            float4 s4 = ((const float4*)(s_red + 256))[lane];
            float inv = 1.f/(s4.x + s4.y + s4.z + s4.w);
            #pragma unroll
            for (int j = 0; j < 16; ++j) p[j] *= inv;

            // PV partial over this wave's m-quarter
            float a[HD];
            #pragma unroll
            for (int d = 0; d < HD; ++d) a[d] = 0.f;
            #pragma unroll
            for (int j = 0; j < 16; ++j) {
                const float* vp = s_vR + (wid*16 + j)*XS + h*20;   // wave-uniform
                float4 v0 = *(const float4*)(vp);
                float4 v1 = *(const float4*)(vp + 4);
                float4 v2 = *(const float4*)(vp + 8);
                float4 v3 = *(const float4*)(vp + 12);
                float v16 = vp[16], v17 = vp[17], v18 = vp[18];
                a[0]=fmaf(v0.x,p[j],a[0]); a[1]=fmaf(v0.y,p[j],a[1]); a[2]=fmaf(v0.z,p[j],a[2]); a[3]=fmaf(v0.w,p[j],a[3]);
                a[4]=fmaf(v1.x,p[j],a[4]); a[5]=fmaf(v1.y,p[j],a[5]); a[6]=fmaf(v1.z,p[j],a[6]); a[7]=fmaf(v1.w,p[j],a[7]);
                a[8]=fmaf(v2.x,p[j],a[8]); a[9]=fmaf(v2.y,p[j],a[9]); a[10]=fmaf(v2.z,p[j],a[10]); a[11]=fmaf(v2.w,p[j],a[11]);
                a[12]=fmaf(v3.x,p[j],a[12]); a[13]=fmaf(v3.y,p[j],a[13]); a[14]=fmaf(v3.z,p[j],a[14]); a[15]=fmaf(v3.w,p[j],a[15]);
                a[16]=fmaf(v16,p[j],a[16]); a[17]=fmaf(v17,p[j],a[17]); a[18]=fmaf(v18,p[j],a[18]);
            }
            // 2-buffer partial reduce
            if (wid < 2) {
                float* ap = s_ap + wid*(L*HD) + lane*HD;
                #pragma unroll
                for (int d = 0; d < HD; ++d) ap[d] = a[d];
            }
            __syncthreads();
            if (wid >= 2) {
                float* ap = s_ap + (wid-2)*(L*HD) + lane*HD;
                #pragma unroll
                for (int d = 0; d < HD; ++d) ap[d] += a[d];
            }
            __syncthreads();
            for (int idx = tid; idx < L*HD; idx += 256) {
                float s = s_ap[idx] + s_ap[L*HD + idx];
                int l = idx / HD, d = idx - l*HD;
                s_q[l*XS + h*HD + d] = s;
            }
            __syncthreads();   // a-slice visible; protects s_ap reuse next head
        }

        // ============ out-proj + residual + LN1 (in-place pre-LN stash) ============
        {
            float ar[D];
            load_row38(s_q + lane*XS, ar);
            float sumw = 0.f, ssqw = 0.f;
            for (int c = wid; c < D; c += 4) {
                const float* w = ow + ((size_t)layer*D + c)*D;
                float acc = ob[layer*D + c];
                #pragma unroll
                for (int k = 0; k < D; ++k) acc = fmaf(ar[k], w[k], acc);
                float t = s_x[lane*XS + c] + acc;
                s_x[lane*XS + c] = t;                    // owner-exclusive slot
                sumw += t; ssqw = fmaf(t, t, ssqw);
            }
            s_red[lane*4 + wid] = sumw;
            s_red[256 + lane*4 + wid] = ssqw;
            __syncthreads();
            float4 s4 = ((const float4*)s_red)[lane];
            float4 q4 = ((const float4*)(s_red + 256))[lane];
            float mu  = (s4.x + s4.y + s4.z + s4.w) * (1.f/38.f);
            float var = (q4.x + q4.y + q4.z + q4.w) * (1.f/38.f) - mu*mu;
            float inv = rsqrtf(var + 1e-5f);
            for (int c = wid; c < D; c += 4) {
                float t = s_x[lane*XS + c];
                s_x[lane*XS + c] = (t - mu)*inv*ln1w[layer*D + c] + ln1b[layer*D + c];
            }
        }
        __syncthreads();   // LN1 result visible (FFN1 reads full rows)

        // ============ FFN1 + exact GELU -> s_f ============
        {
            float xr[D];
            load_row38(s_x + lane*XS, xr);
            for (int c = wid; c < D; c += 4) {
                const float* w = l1w + ((size_t)layer*D + c)*D;
                float acc = l1b[layer*D + c];
                #pragma unroll
                for (int k = 0; k < D; ++k) acc = fmaf(xr[k], w[k], acc);
                s_f[lane*XS + c] = 0.5f*acc*(1.0f + erff(acc*0.70710678118654752f));
            }
        }
        __syncthreads();   // f visible (FFN2 reads full rows)

        // ============ FFN2 + residual + LN2 ============
        {
            float fr[D];
            load_row38(s_f + lane*XS, fr);
            float sumw = 0.f, ssqw = 0.f;
            for (int c = wid; c < D; c += 4) {
                const float* w = l2w + ((size_t)layer*D + c)*D;
                float acc = l2b[layer*D + c];
                #pragma unroll
                for (int k = 0; k < D; ++k) acc = fmaf(fr[k], w[k], acc);
                float t = s_x[lane*XS + c] + acc;
                s_x[lane*XS + c] = t;
                sumw += t; ssqw = fmaf(t, t, ssqw);
            }
            s_red[lane*4 + wid] = sumw;
            s_red[256 + lane*4 + wid] = ssqw;
            __syncthreads();
            float4 s4 = ((const float4*)s_red)[lane];
            float4 q4 = ((const float4*)(s_red + 256))[lane];
            float mu  = (s4.x + s4.y + s4.z + s4.w) * (1.f/38.f);
            float var = (q4.x + q4.y + q4.z + q4.w) * (1.f/38.f) - mu*mu;
            float inv = rsqrtf(var + 1e-5f);
            for (int c = wid; c < D; c += 4) {
                float t = s_x[lane*XS + c];
                s_x[lane*XS + c] = (t - mu)*inv*ln2w[layer*D + c] + ln2b[layer*D + c];
            }
        }
        __syncthreads();   // end of layer (next QKV reads full rows, writes U)
    }

    // ============ pooling + classifier (fp32) ============
    {
        float xr[D];
        load_row38(s_x + lane*XS, xr);
        #pragma unroll
        for (int kk = 0; kk < 2; ++kk) {
            const int k = wid*2 + kk;
            const float* aw = attn_w + k*D;
            float sc = attn_b[k];
            #pragma unroll
            for (int d = 0; d < D; ++d) sc = fmaf(xr[d], aw[d], sc);
            float mx = sc;
            #pragma unroll
            for (int off = 32; off > 0; off >>= 1) mx = fmaxf(mx, __shfl_xor(mx, off));
            float e = __expf(sc - mx);
            float sm = e;
            #pragma unroll
            for (int off = 32; off > 0; off >>= 1) sm += __shfl_xor(sm, off);
            float pr = e / sm;
            out_scores[(size_t)b*(KD*L) + k*L + lane] = pr;
            const float* cw = clf_w + k*D;
            float y = 0.f;
            #pragma unroll
            for (int d = 0; d < D; ++d) y = fmaf(xr[d], cw[d], y);
            float t = pr * y;
            #pragma unroll
            for (int off = 32; off > 0; off >>= 1) t += __shfl_xor(t, off);
            if (lane == 0) out_logits[(size_t)b*KD + k] = t + clf_b[k];
        }
    }
}

extern "C" void kernel_launch(void* const* d_in, const int* in_sizes, int n_in,
                              void* d_out, int out_size, void* d_ws, size_t ws_size,
                              hipStream_t stream) {
    const float* x         = (const float*)d_in[0];
    const float* in_proj_w = (const float*)d_in[1];
    const float* in_proj_b = (const float*)d_in[2];
    const float* out_w     = (const float*)d_in[3];
    const float* out_b     = (const float*)d_in[4];
    const float* lin1_w    = (const float*)d_in[5];
    const float* lin1_b    = (const float*)d_in[6];
    const float* lin2_w    = (const float*)d_in[7];
    const float* lin2_b    = (const float*)d_in[8];
    const float* ln1_w     = (const float*)d_in[9];
    const float* ln1_b     = (const float*)d_in[10];
    const float* ln2_w     = (const float*)d_in[11];
    const float* ln2_b     = (const float*)d_in[12];
    const float* attn_w    = (const float*)d_in[13];
    const float* attn_b    = (const float*)d_in[14];
    const float* clf_w     = (const float*)d_in[15];
    const float* clf_b     = (const float*)d_in[16];

    const int B = in_sizes[0] / (L*D);             // 8192
    float* out_logits = (float*)d_out;             // [B][8]
    float* out_scores = out_logits + (size_t)B*KD; // [B][8][64]

    symptom_v16<<<B, 256, 0, stream>>>(
        x, in_proj_w, in_proj_b, out_w, out_b, lin1_w, lin1_b, lin2_w, lin2_b,
        ln1_w, ln1_b, ln2_w, ln2_b, attn_w, attn_b, clf_w, clf_b,
        out_logits, out_scores);
}

// Round 17
// 1911.811 us; speedup vs baseline: 4.0542x; 1.1692x over previous
//
#include <hip/hip_runtime.h>
#include <math.h>

#define L 64
#define D 38
#define HD 19
#define NL 6
#define KD 8
#define QKV 114

__global__ __launch_bounds__(256, 3) void symptom_v17(
    const float* __restrict__ x_g,
    const float* __restrict__ ipw, const float* __restrict__ ipb,
    const float* __restrict__ ow,  const float* __restrict__ ob,
    const float* __restrict__ l1w, const float* __restrict__ l1b,
    const float* __restrict__ l2w, const float* __restrict__ l2b,
    const float* __restrict__ ln1w, const float* __restrict__ ln1b,
    const float* __restrict__ ln2w, const float* __restrict__ ln2b,
    const float* __restrict__ attn_w, const float* __restrict__ attn_b,
    const float* __restrict__ clf_w,  const float* __restrict__ clf_b,
    float* __restrict__ out_logits,   // [B][8]
    float* __restrict__ out_scores)   // [B][8][64]
{
    const int b    = blockIdx.x;
    const int tid  = threadIdx.x;
    const int lane = tid & 63;                                  // row index
    const int wid  = __builtin_amdgcn_readfirstlane(tid >> 6);  // wave id (col stripe)

    // Column-major [col][row]: per-lane (lane=row) access is consecutive-address
    // -> conflict-free; wave-uniform float4 row-slices stay broadcasts.
    __shared__ __align__(16) float s_xT[D*L];    // 9728 activation
    __shared__ __align__(16) float s_qT[D*L];    // 9728 q / attn-out a
    __shared__ __align__(16) float s_kT[D*L];    // 9728 k [d][m]; FFN f overlays
    __shared__ __align__(16) float s_vT[D*L];    // 9728 v [d][m]
    __shared__ __align__(16) float s_ap[2*L*HD]; // 9728 PV partials (2-buffer)
    __shared__ __align__(16) float s_red[1280];  // 5120 cross-wave exchange (stride 5)
    float* s_fT = s_kT;                          // FFN intermediate overlay
    // total 53,760 B -> 3 blocks/CU

    // ---- stage x: coalesced global read, LDS transpose (one-off conflicts) ----
    const float* xb = x_g + (size_t)b*(L*D);
    for (int i = tid; i < L*D; i += 256) {
        int r = i / D, c = i - r*D;
        s_xT[c*L + r] = xb[i];
    }
    __syncthreads();

    const float scale = 0.22941573387056174f;   // 1/sqrt(19)

    for (int layer = 0; layer < NL; ++layer) {
        // ============ QKV projection (fp32, SGPR weights) ============
        {
            float xr[D];
            #pragma unroll
            for (int k = 0; k < D; ++k) xr[k] = s_xT[k*L + lane];   // conflict-free
            for (int c = wid; c < QKV; c += 4) {                    // c wave-uniform
                const float* w = ipw + ((size_t)layer*QKV + c)*D;
                float acc = ipb[layer*QKV + c];
                #pragma unroll
                for (int k = 0; k < D; ++k) acc = fmaf(xr[k], w[k], acc);
                if (c < 38)      s_qT[c*L + lane] = acc;            // conflict-free
                else if (c < 76) s_kT[(c-38)*L + lane] = acc;
                else             s_vT[(c-76)*L + lane] = acc;
            }
        }
        __syncthreads();   // BAR: q/kT/vT ready

        // ============ attention (fp32, LDS-broadcast operands) ============
        for (int h = 0; h < 2; ++h) {
            float q[HD];
            #pragma unroll
            for (int d = 0; d < HD; ++d) q[d] = s_qT[(h*HD + d)*L + lane];
            // S: p[j] over this wave's m-quarter (d ascending per p)
            float p[16];
            #pragma unroll
            for (int j = 0; j < 16; ++j) p[j] = 0.f;
            #pragma unroll
            for (int d = 0; d < HD; ++d) {
                const float* kp = s_kT + (h*HD + d)*L + wid*16;     // wave-uniform
                float4 k0 = *(const float4*)(kp);
                float4 k1 = *(const float4*)(kp + 4);
                float4 k2 = *(const float4*)(kp + 8);
                float4 k3 = *(const float4*)(kp + 12);
                p[0]=fmaf(k0.x,q[d],p[0]); p[1]=fmaf(k0.y,q[d],p[1]); p[2]=fmaf(k0.z,q[d],p[2]); p[3]=fmaf(k0.w,q[d],p[3]);
                p[4]=fmaf(k1.x,q[d],p[4]); p[5]=fmaf(k1.y,q[d],p[5]); p[6]=fmaf(k1.z,q[d],p[6]); p[7]=fmaf(k1.w,q[d],p[7]);
                p[8]=fmaf(k2.x,q[d],p[8]); p[9]=fmaf(k2.y,q[d],p[9]); p[10]=fmaf(k2.z,q[d],p[10]); p[11]=fmaf(k2.w,q[d],p[11]);
                p[12]=fmaf(k3.x,q[d],p[12]); p[13]=fmaf(k3.y,q[d],p[13]); p[14]=fmaf(k3.z,q[d],p[14]); p[15]=fmaf(k3.w,q[d],p[15]);
            }
            #pragma unroll
            for (int j = 0; j < 16; ++j) p[j] *= scale;
            // softmax across 4 m-quarters (stride-5 exchange: conflict-free)
            float pmax = p[0];
            #pragma unroll
            for (int j = 1; j < 16; ++j) pmax = fmaxf(pmax, p[j]);
            s_red[lane*5 + wid] = pmax;
            __syncthreads();
            float gmax;
            {
                float m0 = s_red[lane*5+0], m1 = s_red[lane*5+1];
                float m2 = s_red[lane*5+2], m3 = s_red[lane*5+3];
                gmax = fmaxf(fmaxf(m0, m1), fmaxf(m2, m3));
            }
            float psum = 0.f;
            #pragma unroll
            for (int j = 0; j < 16; ++j) { p[j] = __expf(p[j]-gmax); psum += p[j]; }
            s_red[640 + lane*5 + wid] = psum;
            __syncthreads();
            {
                float s0 = s_red[640+lane*5+0], s1 = s_red[640+lane*5+1];
                float s2 = s_red[640+lane*5+2], s3 = s_red[640+lane*5+3];
                float inv = 1.f/(s0 + s1 + s2 + s3);
                #pragma unroll
                for (int j = 0; j < 16; ++j) p[j] *= inv;
            }
            // PV partial (d outer, j ascending per accumulator)
            float a[HD];
            #pragma unroll
            for (int d = 0; d < HD; ++d) {
                const float* vp = s_vT + (h*HD + d)*L + wid*16;     // wave-uniform
                float4 v0 = *(const float4*)(vp);
                float4 v1 = *(const float4*)(vp + 4);
                float4 v2 = *(const float4*)(vp + 8);
                float4 v3 = *(const float4*)(vp + 12);
                float acc = 0.f;
                acc=fmaf(v0.x,p[0],acc); acc=fmaf(v0.y,p[1],acc); acc=fmaf(v0.z,p[2],acc); acc=fmaf(v0.w,p[3],acc);
                acc=fmaf(v1.x,p[4],acc); acc=fmaf(v1.y,p[5],acc); acc=fmaf(v1.z,p[6],acc); acc=fmaf(v1.w,p[7],acc);
                acc=fmaf(v2.x,p[8],acc); acc=fmaf(v2.y,p[9],acc); acc=fmaf(v2.z,p[10],acc); acc=fmaf(v2.w,p[11],acc);
                acc=fmaf(v3.x,p[12],acc); acc=fmaf(v3.y,p[13],acc); acc=fmaf(v3.z,p[14],acc); acc=fmaf(v3.w,p[15],acc);
                a[d] = acc;
            }
            // 2-buffer partial reduce (stride-19: conflict-free)
            if (wid < 2) {
                float* ap = s_ap + wid*(L*HD) + lane*HD;
                #pragma unroll
                for (int d = 0; d < HD; ++d) ap[d] = a[d];
            }
            __syncthreads();
            if (wid >= 2) {
                float* ap = s_ap + (wid-2)*(L*HD) + lane*HD;
                #pragma unroll
                for (int d = 0; d < HD; ++d) ap[d] += a[d];
            }
            __syncthreads();
            for (int idx = tid; idx < L*HD; idx += 256) {
                int l = idx & 63, dd = idx >> 6;
                float s = s_ap[l*HD + dd] + s_ap[L*HD + l*HD + dd];
                s_qT[(h*HD + dd)*L + l] = s;    // a overwrites this head's q cols
            }
            __syncthreads();   // a visible; protects s_ap reuse next head
        }

        // ============ out-proj + residual + LN1 (in-place, conflict-free) ============
        {
            float ar[D];
            #pragma unroll
            for (int k = 0; k < D; ++k) ar[k] = s_qT[k*L + lane];
            float sumw = 0.f, ssqw = 0.f;
            for (int c = wid; c < D; c += 4) {
                const float* w = ow + ((size_t)layer*D + c)*D;
                float acc = ob[layer*D + c];
                #pragma unroll
                for (int k = 0; k < D; ++k) acc = fmaf(ar[k], w[k], acc);
                float t = s_xT[c*L + lane] + acc;
                s_xT[c*L + lane] = t;                   // owner-exclusive slot
                sumw += t; ssqw = fmaf(t, t, ssqw);
            }
            s_red[lane*5 + wid] = sumw;
            s_red[640 + lane*5 + wid] = ssqw;
            __syncthreads();
            float mu, inv;
            {
                float s0 = s_red[lane*5+0], s1 = s_red[lane*5+1];
                float s2 = s_red[lane*5+2], s3 = s_red[lane*5+3];
                float q0 = s_red[640+lane*5+0], q1 = s_red[640+lane*5+1];
                float q2 = s_red[640+lane*5+2], q3 = s_red[640+lane*5+3];
                mu  = (s0+s1+s2+s3) * (1.f/38.f);
                float var = (q0+q1+q2+q3) * (1.f/38.f) - mu*mu;
                inv = rsqrtf(var + 1e-5f);
            }
            for (int c = wid; c < D; c += 4) {
                float t = s_xT[c*L + lane];
                s_xT[c*L + lane] = (t - mu)*inv*ln1w[layer*D + c] + ln1b[layer*D + c];
            }
        }
        __syncthreads();   // LN1 rows complete (4 waves wrote disjoint col stripes)

        // ============ FFN1 + exact GELU -> s_fT ============
        {
            float xr[D];
            #pragma unroll
            for (int k = 0; k < D; ++k) xr[k] = s_xT[k*L + lane];
            for (int c = wid; c < D; c += 4) {
                const float* w = l1w + ((size_t)layer*D + c)*D;
                float acc = l1b[layer*D + c];
                #pragma unroll
                for (int k = 0; k < D; ++k) acc = fmaf(xr[k], w[k], acc);
                s_fT[c*L + lane] = 0.5f*acc*(1.0f + erff(acc*0.70710678118654752f));
            }
        }
        __syncthreads();   // f visible

        // ============ FFN2 + residual + LN2 ============
        {
            float fr[D];
            #pragma unroll
            for (int k = 0; k < D; ++k) fr[k] = s_fT[k*L + lane];
            float sumw = 0.f, ssqw = 0.f;
            for (int c = wid; c < D; c += 4) {
                const float* w = l2w + ((size_t)layer*D + c)*D;
                float acc = l2b[layer*D + c];
                #pragma unroll
                for (int k = 0; k < D; ++k) acc = fmaf(fr[k], w[k], acc);
                float t = s_xT[c*L + lane] + acc;
                s_xT[c*L + lane] = t;
                sumw += t; ssqw = fmaf(t, t, ssqw);
            }
            s_red[lane*5 + wid] = sumw;
            s_red[640 + lane*5 + wid] = ssqw;
            __syncthreads();
            float mu, inv;
            {
                float s0 = s_red[lane*5+0], s1 = s_red[lane*5+1];
                float s2 = s_red[lane*5+2], s3 = s_red[lane*5+3];
                float q0 = s_red[640+lane*5+0], q1 = s_red[640+lane*5+1];
                float q2 = s_red[640+lane*5+2], q3 = s_red[640+lane*5+3];
                mu  = (s0+s1+s2+s3) * (1.f/38.f);
                float var = (q0+q1+q2+q3) * (1.f/38.f) - mu*mu;
                inv = rsqrtf(var + 1e-5f);
            }
            for (int c = wid; c < D; c += 4) {
                float t = s_xT[c*L + lane];
                s_xT[c*L + lane] = (t - mu)*inv*ln2w[layer*D + c] + ln2b[layer*D + c];
            }
        }
        __syncthreads();   // end of layer
    }

    // ============ pooling + classifier (fp32) ============
    {
        float xr[D];
        #pragma unroll
        for (int d = 0; d < D; ++d) xr[d] = s_xT[d*L + lane];
        #pragma unroll
        for (int kk = 0; kk < 2; ++kk) {
            const int k = wid*2 + kk;
            const float* aw = attn_w + k*D;
            float sc = attn_b[k];
            #pragma unroll
            for (int d = 0; d < D; ++d) sc = fmaf(xr[d], aw[d], sc);
            float mx = sc;
            #pragma unroll
            for (int off = 32; off > 0; off >>= 1) mx = fmaxf(mx, __shfl_xor(mx, off));
            float e = __expf(sc - mx);
            float sm = e;
            #pragma unroll
            for (int off = 32; off > 0; off >>= 1) sm += __shfl_xor(sm, off);
            float pr = e / sm;
            out_scores[(size_t)b*(KD*L) + k*L + lane] = pr;
            const float* cw = clf_w + k*D;
            float y = 0.f;
            #pragma unroll
            for (int d = 0; d < D; ++d) y = fmaf(xr[d], cw[d], y);
            float t = pr * y;
            #pragma unroll
            for (int off = 32; off > 0; off >>= 1) t += __shfl_xor(t, off);
            if (lane == 0) out_logits[(size_t)b*KD + k] = t + clf_b[k];
        }
    }
}

extern "C" void kernel_launch(void* const* d_in, const int* in_sizes, int n_in,
                              void* d_out, int out_size, void* d_ws, size_t ws_size,
                              hipStream_t stream) {
    const float* x         = (const float*)d_in[0];
    const float* in_proj_w = (const float*)d_in[1];
    const float* in_proj_b = (const float*)d_in[2];
    const float* out_w     = (const float*)d_in[3];
    const float* out_b     = (const float*)d_in[4];
    const float* lin1_w    = (const float*)d_in[5];
    const float* lin1_b    = (const float*)d_in[6];
    const float* lin2_w    = (const float*)d_in[7];
    const float* lin2_b    = (const float*)d_in[8];
    const float* ln1_w     = (const float*)d_in[9];
    const float* ln1_b     = (const float*)d_in[10];
    const float* ln2_w     = (const float*)d_in[11];
    const float* ln2_b     = (const float*)d_in[12];
    const float* attn_w    = (const float*)d_in[13];
    const float* attn_b    = (const float*)d_in[14];
    const float* clf_w     = (const float*)d_in[15];
    const float* clf_b     = (const float*)d_in[16];

    const int B = in_sizes[0] / (L*D);             // 8192
    float* out_logits = (float*)d_out;             // [B][8]
    float* out_scores = out_logits + (size_t)B*KD; // [B][8][64]

    symptom_v17<<<B, 256, 0, stream>>>(
        x, in_proj_w, in_proj_b, out_w, out_b, lin1_w, lin1_b, lin2_w, lin2_b,
        ln1_w, ln1_b, ln2_w, ln2_b, attn_w, attn_b, clf_w, clf_b,
        out_logits, out_scores);
}